// Round 4
// baseline (242.037 us; speedup 1.0000x reference)
//
#include <hip/hip_runtime.h>
#include <stdint.h>

#define N_NODES 100000
#define N_EDGES 600000
#define FEAT 128
#define NTILES 1563            // ceil(100000/64)
#define NTASKS (NTILES * 2)    // x2 N-halves
#define GRID_G 1024            // persistent GEMM grid: 256 CU x 4 blocks

typedef __attribute__((ext_vector_type(8))) short short8;
typedef __attribute__((ext_vector_type(4))) short sv4;
typedef __attribute__((ext_vector_type(4))) float floatx4;

__device__ __forceinline__ short f2bf(float f) {
    unsigned u = __builtin_bit_cast(unsigned, f);
    u = (u + 0x7FFFu + ((u >> 16) & 1u)) >> 16;   // RNE to bf16
    return (short)u;
}
__device__ __forceinline__ float bf2f(short s) {
    unsigned u = ((unsigned)(unsigned short)s) << 16;
    return __builtin_bit_cast(float, u);
}

// Wbt [n=256][k=128] bf16, Wbt[n][k] = concat(W1_top,W1_bot) column n (k-contiguous)
__global__ void cvt_w_kernel(const float* __restrict__ w1, short* __restrict__ wbt) {
    int i = blockIdx.x * 256 + threadIdx.x;   // 32768 = 256*128
    int n = i >> 7, k = i & 127;
    float f = (n < FEAT) ? w1[k * FEAT + n] : w1[(FEAT + k) * FEAT + (n - FEAT)];
    wbt[i] = f2bf(f);
}

// Y[100000][256] bf16 = X[100000][128] @ [W1t | W1b], with b1 folded into cols 0..127.
// Persistent: 1024 blocks, each owns N-half (blockIdx&1), stages 32KB of W ONCE,
// grid-strides over (m-tile, half) tasks. MFMA operand-swapped: D = W_tile * X^T, so
// lane's 4 acc elems = 4 consecutive n -> 8B vector stores.
__global__ __launch_bounds__(256, 4) void node_gemm_kernel(
    const float* __restrict__ x, const short* __restrict__ wbt,
    const float* __restrict__ b1, short* __restrict__ y)
{
    __shared__ short lds_b[128 * 128];   // [n_local][k], 16B-chunk XOR swizzle, 32 KB

    const int tid  = threadIdx.x;
    const int lane = tid & 63;
    const int wave = tid >> 6;
    const int nl   = lane & 15;
    const int q    = lane >> 4;
    const int swz  = nl & 7;
    const int nh   = blockIdx.x & 1;     // task & 1 invariant (GRID_G even)

    // stage this block's half of Wbt once; chunk kc stored at slot kc ^ (n&7)
#pragma unroll
    for (int j0 = 0; j0 < 2048; j0 += 256) {
        int j = j0 + tid;
        int n = j >> 4, kc = j & 15;
        short8 v = *(const short8*)(wbt + (nh * 128 + n) * 128 + kc * 8);
        *(short8*)(lds_b + n * 128 + ((kc ^ (n & 7)) << 3)) = v;
    }
    __syncthreads();

    int task = blockIdx.x;
    float xf[32];
    {   // prefetch first tile's X: lane -> row, xf[s*8+j] = X[node][32s+8q+j]
        int node = (task >> 1) * 64 + wave * 16 + nl;
        int nsrc = (node < N_NODES) ? node : 0;
        const float* p = x + (size_t)nsrc * FEAT + q * 8;
#pragma unroll
        for (int s = 0; s < 4; ++s)
#pragma unroll
            for (int j = 0; j < 8; ++j) xf[s * 8 + j] = p[s * 32 + j];
    }

    for (; task < NTASKS; task += GRID_G) {
        const int node = (task >> 1) * 64 + wave * 16 + nl;

        // convert current X tile to bf16 B-fragments
        short8 a[4];
#pragma unroll
        for (int s = 0; s < 4; ++s) {
            short8 av;
#pragma unroll
            for (int j = 0; j < 8; ++j) av[j] = f2bf(xf[s * 8 + j]);
            a[s] = av;
        }

        // prefetch next task's X during the MFMA chain
        int task2 = task + GRID_G;
        if (task2 < NTASKS) {
            int node2 = (task2 >> 1) * 64 + wave * 16 + nl;
            int nsrc = (node2 < N_NODES) ? node2 : 0;
            const float* p = x + (size_t)nsrc * FEAT + q * 8;
#pragma unroll
            for (int s = 0; s < 4; ++s)
#pragma unroll
                for (int j = 0; j < 8; ++j) xf[s * 8 + j] = p[s * 32 + j];
        }

        floatx4 acc[8];
#pragma unroll
        for (int nt = 0; nt < 8; ++nt) acc[nt] = (floatx4)(0.0f);

#pragma unroll
        for (int s = 0; s < 4; ++s) {
            const int koff = ((s * 4 + q) ^ swz) << 3;   // swizzled 16B chunk (shorts)
#pragma unroll
            for (int nt = 0; nt < 8; ++nt) {
                // A = W rows [nt*16+nl][32s+8q+j]; B = X^T; D[q*4+r][nl] = Y[node(nl)][...]
                short8 af = *(const short8*)(lds_b + (nt * 16 + nl) * 128 + koff);
                acc[nt] = __builtin_amdgcn_mfma_f32_16x16x32_bf16(af, a[s], acc[nt], 0, 0, 0);
            }
        }

        if (node < N_NODES) {
            short* yr = y + (size_t)node * 256 + nh * 128 + q * 4;
            if (nh == 0) {   // fold b1 into the u-half
#pragma unroll
                for (int nt = 0; nt < 8; ++nt) {
                    floatx4 bb = *(const floatx4*)(b1 + nt * 16 + q * 4);
                    sv4 o;
                    o[0] = f2bf(acc[nt][0] + bb[0]); o[1] = f2bf(acc[nt][1] + bb[1]);
                    o[2] = f2bf(acc[nt][2] + bb[2]); o[3] = f2bf(acc[nt][3] + bb[3]);
                    *(sv4*)(yr + nt * 16) = o;
                }
            } else {
#pragma unroll
                for (int nt = 0; nt < 8; ++nt) {
                    sv4 o;
                    o[0] = f2bf(acc[nt][0]); o[1] = f2bf(acc[nt][1]);
                    o[2] = f2bf(acc[nt][2]); o[3] = f2bf(acc[nt][3]);
                    *(sv4*)(yr + nt * 16) = o;
                }
            }
        }
    }
}

// Per-edge: out = sigmoid(relu(Yu[r] + Yv[c]) . W2 + b2)   (b1 pre-folded into Yu)
// 16 lanes/edge, 8 feats/lane; batch-4 double-buffered gathers for MLP.
__global__ __launch_bounds__(256) void edge_kernel(
    const short* __restrict__ y, const int* __restrict__ eidx,
    const float* __restrict__ w2, const float* __restrict__ b2,
    float* __restrict__ out)
{
    const int l = threadIdx.x & 15;

    float w2r[8];
#pragma unroll
    for (int j = 0; j < 8; ++j) w2r[j] = w2[l * 8 + j];
    const float bias2 = b2[0];

    const int slot   = blockIdx.x * 16 + (threadIdx.x >> 4);
    const int stride = gridDim.x * 16;

    short8 cu[4], cv[4], nu[4], nv[4];
#pragma unroll
    for (int b = 0; b < 4; ++b) {
        int e = slot + b * stride;
        if (e < N_EDGES) {
            int r = eidx[e], c = eidx[N_EDGES + e];
            cu[b] = *(const short8*)(y + (size_t)r * 256 + l * 8);
            cv[b] = *(const short8*)(y + (size_t)c * 256 + 128 + l * 8);
        }
    }

    for (int eb = slot; eb < N_EDGES; eb += 4 * stride) {
        int nb = eb + 4 * stride;
#pragma unroll
        for (int b = 0; b < 4; ++b) {   // issue next batch's gathers first
            int e = nb + b * stride;
            if (e < N_EDGES) {
                int r = eidx[e], c = eidx[N_EDGES + e];
                nu[b] = *(const short8*)(y + (size_t)r * 256 + l * 8);
                nv[b] = *(const short8*)(y + (size_t)c * 256 + 128 + l * 8);
            }
        }
#pragma unroll
        for (int b = 0; b < 4; ++b) {   // compute current batch
            int e = eb + b * stride;
            if (e < N_EDGES) {
                float p = 0.0f;
#pragma unroll
                for (int j = 0; j < 8; ++j) {
                    float h = bf2f(cu[b][j]) + bf2f(cv[b][j]);
                    p = fmaf(fmaxf(h, 0.0f), w2r[j], p);
                }
                p += __shfl_xor(p, 1);
                p += __shfl_xor(p, 2);
                p += __shfl_xor(p, 4);
                p += __shfl_xor(p, 8);
                if (l == 0) out[e] = 1.0f / (1.0f + __expf(-(p + bias2)));
            }
        }
#pragma unroll
        for (int b = 0; b < 4; ++b) { cu[b] = nu[b]; cv[b] = nv[b]; }
    }
}

extern "C" void kernel_launch(void* const* d_in, const int* in_sizes, int n_in,
                              void* d_out, int out_size, void* d_ws, size_t ws_size,
                              hipStream_t stream) {
    const float* x  = (const float*)d_in[0];
    const int*   ei = (const int*)d_in[1];
    const float* W1 = (const float*)d_in[2];
    const float* b1 = (const float*)d_in[3];
    const float* W2 = (const float*)d_in[4];
    const float* b2 = (const float*)d_in[5];
    float* out = (float*)d_out;

    short* ybf = (short*)d_ws;                          // 100000*256 shorts = 51.2 MB
    short* wbt = ybf + (size_t)N_NODES * 256;           // 32768 shorts

    cvt_w_kernel<<<32768 / 256, 256, 0, stream>>>(W1, wbt);
    node_gemm_kernel<<<GRID_G, 256, 0, stream>>>(x, wbt, b1, ybf);
    edge_kernel<<<2048, 256, 0, stream>>>(ybf, ei, W2, b2, out);
}

// Round 5
// 167.191 us; speedup vs baseline: 1.4477x; 1.4477x over previous
//
#include <hip/hip_runtime.h>
#include <stdint.h>

#define N_NODES 100000
#define N_EDGES 600000
#define FEAT 128
#define BLK_M 128

typedef __attribute__((ext_vector_type(8))) short short8;
typedef __attribute__((ext_vector_type(4))) float floatx4;

__device__ __forceinline__ short f2bf(float f) {
    unsigned u = __builtin_bit_cast(unsigned, f);
    u = (u + 0x7FFFu + ((u >> 16) & 1u)) >> 16;   // RNE to bf16
    return (short)u;
}
__device__ __forceinline__ float bf2f(short s) {
    unsigned u = ((unsigned)(unsigned short)s) << 16;
    return __builtin_bit_cast(float, u);
}

// Wbt [n=256][k=128] bf16, Wbt[n][k] = concat(W1_top,W1_bot) column n (k-contiguous)
__global__ void cvt_w_kernel(const float* __restrict__ w1, short* __restrict__ wbt) {
    int i = blockIdx.x * 256 + threadIdx.x;   // 32768 = 256*128
    int n = i >> 7, k = i & 127;
    float f = (n < FEAT) ? w1[k * FEAT + n] : w1[(FEAT + k) * FEAT + (n - FEAT)];
    wbt[i] = f2bf(f);
}

// Y[100000][256] bf16 = X[100000][128] @ [W1t | W1b], b1 folded into cols 0..127.
// Round-1-verified structure (chunk-major LDS, full Y-rows per block, 0 bank conflicts,
// exact 50MB writes) re-parameterized: 512 threads, M-tile 128, 8 waves share the
// 64KB W tile -> 2 blocks/CU = 16 waves/CU (2x round-1's occupancy cap), staging halved.
__global__ __launch_bounds__(512, 4) void node_gemm_kernel(
    const float* __restrict__ x, const short* __restrict__ wbt,
    const float* __restrict__ b1, short* __restrict__ y)
{
    __shared__ short lds_b[16 * 256 * 8];   // chunk-major [c=k/8][n], 64 KB

    const int tid = threadIdx.x;
    for (int j = tid; j < 16 * 256; j += 512) {
        int n = j & 255, c = j >> 8;
        short8 v = *(const short8*)(wbt + n * 128 + c * 8);
        *(short8*)(lds_b + ((c << 8) + n) * 8) = v;
    }
    __syncthreads();

    const int lane = tid & 63;
    const int wave = tid >> 6;           // 0..7
    const int nl = lane & 15;
    const int q  = lane >> 4;
    const int m0 = blockIdx.x * BLK_M + wave * 16;

    // A-fragment: lane holds A[m=nl][k=32s+8q+j], loaded fp32 and converted
    const int node = m0 + nl;
    const int nsrc = (node < N_NODES) ? node : 0;
    short8 a[4];
#pragma unroll
    for (int s = 0; s < 4; ++s) {
        const float* p = x + (size_t)nsrc * FEAT + s * 32 + q * 8;
        short8 av;
#pragma unroll
        for (int j = 0; j < 8; ++j) av[j] = f2bf(p[j]);
        a[s] = av;
    }

    // b1 fold values: n = nt*16 + nl for nt<8 (u-half of Y)
    float b1v[8];
#pragma unroll
    for (int nt = 0; nt < 8; ++nt) b1v[nt] = b1[nt * 16 + nl];

    floatx4 acc[16];
#pragma unroll
    for (int nt = 0; nt < 16; ++nt) acc[nt] = (floatx4)(0.0f);

#pragma unroll
    for (int s = 0; s < 4; ++s) {
        const int crow = (s * 4 + q) << 8;   // chunk c = s*4+q, row base c*256
#pragma unroll
        for (int nt = 0; nt < 16; ++nt) {
            short8 bf = *(const short8*)(lds_b + ((crow + nt * 16 + nl) << 3));
            acc[nt] = __builtin_amdgcn_mfma_f32_16x16x32_bf16(a[s], bf, acc[nt], 0, 0, 0);
        }
    }

    // C/D: lane holds D[m = q*4 + r][n = nt*16 + nl]
#pragma unroll
    for (int r = 0; r < 4; ++r) {
        int m = m0 + q * 4 + r;
        if (m >= N_NODES) continue;
        short* yr = y + (size_t)m * 256 + nl;
#pragma unroll
        for (int nt = 0; nt < 8; ++nt) yr[nt * 16] = f2bf(acc[nt][r] + b1v[nt]);
#pragma unroll
        for (int nt = 8; nt < 16; ++nt) yr[nt * 16] = f2bf(acc[nt][r]);
    }
}

// Per-edge: out = sigmoid(relu(Yu[r] + Yv[c]) . W2 + b2)   (b1 pre-folded into Yu)
// 16 lanes/edge, 8 feats/lane; batch-4 double-buffered gathers. (Verified in round 4.)
__global__ __launch_bounds__(256) void edge_kernel(
    const short* __restrict__ y, const int* __restrict__ eidx,
    const float* __restrict__ w2, const float* __restrict__ b2,
    float* __restrict__ out)
{
    const int l = threadIdx.x & 15;

    float w2r[8];
#pragma unroll
    for (int j = 0; j < 8; ++j) w2r[j] = w2[l * 8 + j];
    const float bias2 = b2[0];

    const int slot   = blockIdx.x * 16 + (threadIdx.x >> 4);
    const int stride = gridDim.x * 16;

    short8 cu[4], cv[4], nu[4], nv[4];
#pragma unroll
    for (int b = 0; b < 4; ++b) {
        int e = slot + b * stride;
        if (e < N_EDGES) {
            int r = eidx[e], c = eidx[N_EDGES + e];
            cu[b] = *(const short8*)(y + (size_t)r * 256 + l * 8);
            cv[b] = *(const short8*)(y + (size_t)c * 256 + 128 + l * 8);
        }
    }

    for (int eb = slot; eb < N_EDGES; eb += 4 * stride) {
        int nb = eb + 4 * stride;
#pragma unroll
        for (int b = 0; b < 4; ++b) {   // issue next batch's gathers first
            int e = nb + b * stride;
            if (e < N_EDGES) {
                int r = eidx[e], c = eidx[N_EDGES + e];
                nu[b] = *(const short8*)(y + (size_t)r * 256 + l * 8);
                nv[b] = *(const short8*)(y + (size_t)c * 256 + 128 + l * 8);
            }
        }
#pragma unroll
        for (int b = 0; b < 4; ++b) {   // compute current batch
            int e = eb + b * stride;
            if (e < N_EDGES) {
                float p = 0.0f;
#pragma unroll
                for (int j = 0; j < 8; ++j) {
                    float h = bf2f(cu[b][j]) + bf2f(cv[b][j]);
                    p = fmaf(fmaxf(h, 0.0f), w2r[j], p);
                }
                p += __shfl_xor(p, 1);
                p += __shfl_xor(p, 2);
                p += __shfl_xor(p, 4);
                p += __shfl_xor(p, 8);
                if (l == 0) out[e] = 1.0f / (1.0f + __expf(-(p + bias2)));
            }
        }
#pragma unroll
        for (int b = 0; b < 4; ++b) { cu[b] = nu[b]; cv[b] = nv[b]; }
    }
}

extern "C" void kernel_launch(void* const* d_in, const int* in_sizes, int n_in,
                              void* d_out, int out_size, void* d_ws, size_t ws_size,
                              hipStream_t stream) {
    const float* x  = (const float*)d_in[0];
    const int*   ei = (const int*)d_in[1];
    const float* W1 = (const float*)d_in[2];
    const float* b1 = (const float*)d_in[3];
    const float* W2 = (const float*)d_in[4];
    const float* b2 = (const float*)d_in[5];
    float* out = (float*)d_out;

    short* ybf = (short*)d_ws;                          // 100000*256 shorts = 51.2 MB
    short* wbt = ybf + (size_t)N_NODES * 256;           // 32768 shorts

    cvt_w_kernel<<<32768 / 256, 256, 0, stream>>>(W1, wbt);

    int mblocks = (N_NODES + BLK_M - 1) / BLK_M;        // 782
    node_gemm_kernel<<<mblocks, 512, 0, stream>>>(x, wbt, b1, ybf);

    edge_kernel<<<2048, 256, 0, stream>>>(ybf, ei, W2, b2, out);
}

// Round 6
// 158.828 us; speedup vs baseline: 1.5239x; 1.0527x over previous
//
#include <hip/hip_runtime.h>
#include <stdint.h>

#define N_NODES 100000
#define N_EDGES 600000
#define FEAT 128
#define BLK_M 128

typedef __attribute__((ext_vector_type(8))) short short8;
typedef __attribute__((ext_vector_type(4))) float floatx4;

__device__ __forceinline__ short f2bf(float f) {
    unsigned u = __builtin_bit_cast(unsigned, f);
    u = (u + 0x7FFFu + ((u >> 16) & 1u)) >> 16;   // RNE to bf16
    return (short)u;
}
__device__ __forceinline__ float bf2f(short s) {
    unsigned u = ((unsigned)(unsigned short)s) << 16;
    return __builtin_bit_cast(float, u);
}

// Wbt [n=256][k=128] bf16, Wbt[n][k] = concat(W1_top,W1_bot) column n (k-contiguous)
__global__ void cvt_w_kernel(const float* __restrict__ w1, short* __restrict__ wbt) {
    int i = blockIdx.x * 256 + threadIdx.x;   // 32768 = 256*128
    int n = i >> 7, k = i & 127;
    float f = (n < FEAT) ? w1[k * FEAT + n] : w1[(FEAT + k) * FEAT + (n - FEAT)];
    wbt[i] = f2bf(f);
}

// Y[100000][256] bf16 = X[100000][128] @ [W1t | W1b], b1 folded into cols 0..127.
// (unchanged from round 5 — verified, all dispatches <53us)
__global__ __launch_bounds__(512, 4) void node_gemm_kernel(
    const float* __restrict__ x, const short* __restrict__ wbt,
    const float* __restrict__ b1, short* __restrict__ y)
{
    __shared__ short lds_b[16 * 256 * 8];   // chunk-major [c=k/8][n], 64 KB

    const int tid = threadIdx.x;
    for (int j = tid; j < 16 * 256; j += 512) {
        int n = j & 255, c = j >> 8;
        short8 v = *(const short8*)(wbt + n * 128 + c * 8);
        *(short8*)(lds_b + ((c << 8) + n) * 8) = v;
    }
    __syncthreads();

    const int lane = tid & 63;
    const int wave = tid >> 6;           // 0..7
    const int nl = lane & 15;
    const int q  = lane >> 4;
    const int m0 = blockIdx.x * BLK_M + wave * 16;

    const int node = m0 + nl;
    const int nsrc = (node < N_NODES) ? node : 0;
    short8 a[4];
#pragma unroll
    for (int s = 0; s < 4; ++s) {
        const float* p = x + (size_t)nsrc * FEAT + s * 32 + q * 8;
        short8 av;
#pragma unroll
        for (int j = 0; j < 8; ++j) av[j] = f2bf(p[j]);
        a[s] = av;
    }

    float b1v[8];
#pragma unroll
    for (int nt = 0; nt < 8; ++nt) b1v[nt] = b1[nt * 16 + nl];

    floatx4 acc[16];
#pragma unroll
    for (int nt = 0; nt < 16; ++nt) acc[nt] = (floatx4)(0.0f);

#pragma unroll
    for (int s = 0; s < 4; ++s) {
        const int crow = (s * 4 + q) << 8;   // chunk c = s*4+q, row base c*256
#pragma unroll
        for (int nt = 0; nt < 16; ++nt) {
            short8 bf = *(const short8*)(lds_b + ((crow + nt * 16 + nl) << 3));
            acc[nt] = __builtin_amdgcn_mfma_f32_16x16x32_bf16(a[s], bf, acc[nt], 0, 0, 0);
        }
    }

    // C/D: lane holds D[m = q*4 + r][n = nt*16 + nl]
#pragma unroll
    for (int r = 0; r < 4; ++r) {
        int m = m0 + q * 4 + r;
        if (m >= N_NODES) continue;
        short* yr = y + (size_t)m * 256 + nl;
#pragma unroll
        for (int nt = 0; nt < 8; ++nt) yr[nt * 16] = f2bf(acc[nt][r] + b1v[nt]);
#pragma unroll
        for (int nt = 8; nt < 16; ++nt) yr[nt * 16] = f2bf(acc[nt][r]);
    }
}

// Per-edge: out = sigmoid(relu(Yu[r] + Yv[c]) . W2 + b2)   (b1 pre-folded into Yu)
// Batch-4 CONSECUTIVE edges per slot-iteration, no register double-buffering:
//   - 2x int4 index loads replace 8 scalar eidx loads
//   - 8 independent gathers in flight (4x the MLP of the round-1 version)
//   - out[eb..eb+3] stored as one float4 from lane 0
__global__ __launch_bounds__(256) void edge_kernel(
    const short* __restrict__ y, const int* __restrict__ eidx,
    const float* __restrict__ w2, const float* __restrict__ b2,
    float* __restrict__ out)
{
    const int l = threadIdx.x & 15;

    float w2r[8];
#pragma unroll
    for (int j = 0; j < 8; ++j) w2r[j] = w2[l * 8 + j];
    const float bias2 = b2[0];

    const int slot   = blockIdx.x * 16 + (threadIdx.x >> 4);
    const int nslots = gridDim.x * 16;               // 32768

    for (int eb = slot * 4; eb < N_EDGES; eb += nslots * 4) {
        // N_EDGES % 4 == 0 and eb % 4 == 0 -> int4 loads never straddle the end
        int4 rr = *(const int4*)(eidx + eb);
        int4 cc = *(const int4*)(eidx + N_EDGES + eb);

        short8 u0 = *(const short8*)(y + (size_t)rr.x * 256 + l * 8);
        short8 u1 = *(const short8*)(y + (size_t)rr.y * 256 + l * 8);
        short8 u2 = *(const short8*)(y + (size_t)rr.z * 256 + l * 8);
        short8 u3 = *(const short8*)(y + (size_t)rr.w * 256 + l * 8);
        short8 v0 = *(const short8*)(y + (size_t)cc.x * 256 + 128 + l * 8);
        short8 v1 = *(const short8*)(y + (size_t)cc.y * 256 + 128 + l * 8);
        short8 v2 = *(const short8*)(y + (size_t)cc.z * 256 + 128 + l * 8);
        short8 v3 = *(const short8*)(y + (size_t)cc.w * 256 + 128 + l * 8);

        float p0 = 0.0f, p1 = 0.0f, p2 = 0.0f, p3 = 0.0f;
#pragma unroll
        for (int j = 0; j < 8; ++j) {
            p0 = fmaf(fmaxf(bf2f(u0[j]) + bf2f(v0[j]), 0.0f), w2r[j], p0);
            p1 = fmaf(fmaxf(bf2f(u1[j]) + bf2f(v1[j]), 0.0f), w2r[j], p1);
            p2 = fmaf(fmaxf(bf2f(u2[j]) + bf2f(v2[j]), 0.0f), w2r[j], p2);
            p3 = fmaf(fmaxf(bf2f(u3[j]) + bf2f(v3[j]), 0.0f), w2r[j], p3);
        }
#pragma unroll
        for (int d = 1; d < 16; d <<= 1) {
            p0 += __shfl_xor(p0, d);
            p1 += __shfl_xor(p1, d);
            p2 += __shfl_xor(p2, d);
            p3 += __shfl_xor(p3, d);
        }

        if (l == 0) {
            floatx4 o;
            o[0] = 1.0f / (1.0f + __expf(-(p0 + bias2)));
            o[1] = 1.0f / (1.0f + __expf(-(p1 + bias2)));
            o[2] = 1.0f / (1.0f + __expf(-(p2 + bias2)));
            o[3] = 1.0f / (1.0f + __expf(-(p3 + bias2)));
            *(floatx4*)(out + eb) = o;
        }
    }
}

extern "C" void kernel_launch(void* const* d_in, const int* in_sizes, int n_in,
                              void* d_out, int out_size, void* d_ws, size_t ws_size,
                              hipStream_t stream) {
    const float* x  = (const float*)d_in[0];
    const int*   ei = (const int*)d_in[1];
    const float* W1 = (const float*)d_in[2];
    const float* b1 = (const float*)d_in[3];
    const float* W2 = (const float*)d_in[4];
    const float* b2 = (const float*)d_in[5];
    float* out = (float*)d_out;

    short* ybf = (short*)d_ws;                          // 100000*256 shorts = 51.2 MB
    short* wbt = ybf + (size_t)N_NODES * 256;           // 32768 shorts

    cvt_w_kernel<<<32768 / 256, 256, 0, stream>>>(W1, wbt);

    int mblocks = (N_NODES + BLK_M - 1) / BLK_M;        // 782
    node_gemm_kernel<<<mblocks, 512, 0, stream>>>(x, wbt, b1, ybf);

    edge_kernel<<<2048, 256, 0, stream>>>(ybf, ei, W2, b2, out);
}